// Round 1
// baseline (1213.253 us; speedup 1.0000x reference)
//
#include <hip/hip_runtime.h>

#define NN 50000
#define NE 800000
#define DD 64

// Transpose W1 and W2 (64x64 each) into workspace so the per-row dot products
// read consecutive wave-uniform addresses (-> scalar loads).
__global__ __launch_bounds__(256) void k_transpose(const float* __restrict__ W1,
                                                   const float* __restrict__ W2,
                                                   float* __restrict__ W1T,
                                                   float* __restrict__ W2T) {
    int t = blockIdx.x * 256 + threadIdx.x;
    if (t < DD * DD) {
        int r = t >> 6, c = t & 63;
        W1T[c * DD + r] = W1[t];
        W2T[c * DD + r] = W2[t];
    }
}

// node_x[dst[e]] += edge_feat[e]  (fp32 atomics). 16 threads per edge, float4 each.
__global__ __launch_bounds__(256) void k_scatter(const float* __restrict__ ef,
                                                 const int* __restrict__ dst,
                                                 float* __restrict__ nx) {
    long tid = (long)blockIdx.x * 256 + threadIdx.x;
    int e = (int)(tid >> 4);
    if (e >= NE) return;
    int c = ((int)tid & 15) << 2;
    int d = dst[e];
    float4 v = *(const float4*)(ef + (long)e * DD + c);
    float* p = nx + (long)d * DD + c;
    atomicAdd(p + 0, v.x);
    atomicAdd(p + 1, v.y);
    atomicAdd(p + 2, v.z);
    atomicAdd(p + 3, v.w);
}

// h_pre = node_x @ W1   (per-node, 16x fewer FLOPs than per-edge)
__global__ __launch_bounds__(256) void k_node_mlp(const float* __restrict__ nx,
                                                  const float* __restrict__ W1T,
                                                  float* __restrict__ hp) {
    int n = blockIdx.x * 256 + threadIdx.x;
    if (n >= NN) return;
    float x[DD];
    const float4* xr = (const float4*)(nx + (long)n * DD);
#pragma unroll
    for (int i = 0; i < DD / 4; ++i) {
        float4 v = xr[i];
        x[4 * i + 0] = v.x; x[4 * i + 1] = v.y;
        x[4 * i + 2] = v.z; x[4 * i + 3] = v.w;
    }
    float4* o = (float4*)(hp + (long)n * DD);
    for (int j = 0; j < DD; j += 4) {
        const float* w0 = W1T + (j + 0) * DD;
        const float* w1 = W1T + (j + 1) * DD;
        const float* w2 = W1T + (j + 2) * DD;
        const float* w3 = W1T + (j + 3) * DD;
        float a0 = 0.f, a1 = 0.f, a2 = 0.f, a3 = 0.f;
#pragma unroll
        for (int k = 0; k < DD; ++k) {
            float hk = x[k];
            a0 = fmaf(hk, w0[k], a0);
            a1 = fmaf(hk, w1[k], a1);
            a2 = fmaf(hk, w2[k], a2);
            a3 = fmaf(hk, w3[k], a3);
        }
        float4 r; r.x = a0; r.y = a1; r.z = a2; r.w = a3;
        o[j >> 2] = r;
    }
}

// edge_out = 0.5 * (relu(h_pre[src] + h_pre[dst] + b1) @ W2 + b2)
__global__ __launch_bounds__(256) void k_edge_mlp(const float* __restrict__ hp,
                                                  const int* __restrict__ src,
                                                  const int* __restrict__ dst,
                                                  const float* __restrict__ b1,
                                                  const float* __restrict__ W2T,
                                                  const float* __restrict__ b2,
                                                  float* __restrict__ out) {
    int e = blockIdx.x * 256 + threadIdx.x;
    if (e >= NE) return;
    int s = src[e], d = dst[e];
    const float4* ps = (const float4*)(hp + (long)s * DD);
    const float4* pd = (const float4*)(hp + (long)d * DD);
    float h[DD];
#pragma unroll
    for (int i = 0; i < DD / 4; ++i) {
        float4 a = ps[i];
        float4 b = pd[i];
        float4 bb = ((const float4*)b1)[i];
        h[4 * i + 0] = fmaxf(a.x + b.x + bb.x, 0.f);
        h[4 * i + 1] = fmaxf(a.y + b.y + bb.y, 0.f);
        h[4 * i + 2] = fmaxf(a.z + b.z + bb.z, 0.f);
        h[4 * i + 3] = fmaxf(a.w + b.w + bb.w, 0.f);
    }
    float4* o = (float4*)(out + (long)e * DD);
    for (int j = 0; j < DD; j += 4) {
        const float* w0 = W2T + (j + 0) * DD;
        const float* w1 = W2T + (j + 1) * DD;
        const float* w2 = W2T + (j + 2) * DD;
        const float* w3 = W2T + (j + 3) * DD;
        float a0 = b2[j + 0], a1 = b2[j + 1], a2 = b2[j + 2], a3 = b2[j + 3];
#pragma unroll
        for (int k = 0; k < DD; ++k) {
            float hk = h[k];
            a0 = fmaf(hk, w0[k], a0);
            a1 = fmaf(hk, w1[k], a1);
            a2 = fmaf(hk, w2[k], a2);
            a3 = fmaf(hk, w3[k], a3);
        }
        float4 r;
        r.x = 0.5f * a0; r.y = 0.5f * a1; r.z = 0.5f * a2; r.w = 0.5f * a3;
        o[j >> 2] = r;
    }
}

extern "C" void kernel_launch(void* const* d_in, const int* in_sizes, int n_in,
                              void* d_out, int out_size, void* d_ws, size_t ws_size,
                              hipStream_t stream) {
    const float* edge_feat = (const float*)d_in[0];
    const int*   src       = (const int*)d_in[1];
    const int*   dst       = (const int*)d_in[2];
    const float* W1        = (const float*)d_in[3];
    const float* b1        = (const float*)d_in[4];
    const float* W2        = (const float*)d_in[5];
    const float* b2        = (const float*)d_in[6];
    float* out = (float*)d_out;

    char* ws = (char*)d_ws;
    float* node_x = (float*)ws;                                   // NN*DD f32
    float* h_pre  = (float*)(ws + (size_t)NN * DD * 4);           // NN*DD f32
    float* W1T    = (float*)(ws + (size_t)2 * NN * DD * 4);       // 64*64
    float* W2T    = W1T + DD * DD;                                // 64*64

    hipMemsetAsync(node_x, 0, (size_t)NN * DD * 4, stream);
    k_transpose<<<(DD * DD + 255) / 256, 256, 0, stream>>>(W1, W2, W1T, W2T);
    k_scatter<<<(int)(((long)NE * 16 + 255) / 256), 256, 0, stream>>>(edge_feat, dst, node_x);
    k_node_mlp<<<(NN + 255) / 256, 256, 0, stream>>>(node_x, W1T, h_pre);
    k_edge_mlp<<<(NE + 255) / 256, 256, 0, stream>>>(h_pre, src, dst, b1, W2T, b2, out);
}

// Round 2
// 734.628 us; speedup vs baseline: 1.6515x; 1.6515x over previous
//
#include <hip/hip_runtime.h>

#define NN 50000
#define NE 800000
#define DD 64
#define NB 196   // ceil(NN/256)

// ---- weight transpose (W[k][j] -> WT[j][k]) ----
__global__ __launch_bounds__(256) void k_transpose(const float* __restrict__ W1,
                                                   const float* __restrict__ W2,
                                                   float* __restrict__ W1T,
                                                   float* __restrict__ W2T) {
    int t = blockIdx.x * 256 + threadIdx.x;
    if (t < DD * DD) {
        int r = t >> 6, c = t & 63;
        W1T[c * DD + r] = W1[t];
        W2T[c * DD + r] = W2[t];
    }
}

// ---- CSR build: histogram of dst ----
__global__ __launch_bounds__(256) void k_hist(const int* __restrict__ dst,
                                              int* __restrict__ cnt) {
    int e = blockIdx.x * 256 + threadIdx.x;
    if (e < NE) atomicAdd(&cnt[dst[e]], 1);
}

// ---- scan pass 1: per-block sums of cnt ----
__global__ __launch_bounds__(256) void k_block_sum(const int* __restrict__ cnt,
                                                   int* __restrict__ bsum) {
    __shared__ int s[256];
    int i = blockIdx.x * 256 + threadIdx.x;
    s[threadIdx.x] = (i < NN) ? cnt[i] : 0;
    __syncthreads();
    for (int o = 128; o > 0; o >>= 1) {
        if (threadIdx.x < o) s[threadIdx.x] += s[threadIdx.x + o];
        __syncthreads();
    }
    if (threadIdx.x == 0) bsum[blockIdx.x] = s[0];
}

// ---- scan pass 2: exclusive scan of NB block sums (single block) ----
__global__ __launch_bounds__(256) void k_scan_bsum(int* __restrict__ bsum) {
    __shared__ int s[256];
    int t = threadIdx.x;
    int v = (t < NB) ? bsum[t] : 0;
    s[t] = v;
    __syncthreads();
    for (int o = 1; o < 256; o <<= 1) {
        int x = (t >= o) ? s[t - o] : 0;
        __syncthreads();
        s[t] += x;
        __syncthreads();
    }
    if (t < NB) bsum[t] = s[t] - v;  // exclusive
}

// ---- scan pass 3: final exclusive offsets; write row_start and cursor ----
__global__ __launch_bounds__(256) void k_scan_final(const int* __restrict__ cnt,
                                                    const int* __restrict__ bsum,
                                                    int* __restrict__ row_start,
                                                    int* __restrict__ cursor) {
    __shared__ int s[256];
    int t = threadIdx.x;
    int i = blockIdx.x * 256 + t;
    int v = (i < NN) ? cnt[i] : 0;
    s[t] = v;
    __syncthreads();
    for (int o = 1; o < 256; o <<= 1) {
        int x = (t >= o) ? s[t - o] : 0;
        __syncthreads();
        s[t] += x;
        __syncthreads();
    }
    int excl = s[t] - v + bsum[blockIdx.x];
    if (i < NN) {
        row_start[i] = excl;
        cursor[i]    = excl;
        if (i == NN - 1) row_start[NN] = excl + v;  // == NE
    }
}

// ---- counting sort: scatter edge ids into dst-sorted order ----
__global__ __launch_bounds__(256) void k_reorder(const int* __restrict__ dst,
                                                 int* __restrict__ cursor,
                                                 int* __restrict__ eid) {
    int e = blockIdx.x * 256 + threadIdx.x;
    if (e < NE) {
        int pos = atomicAdd(&cursor[dst[e]], 1);
        eid[pos] = e;
    }
}

// ---- gather-sum: one wave per node, lane l accumulates feature l ----
__global__ __launch_bounds__(256) void k_gather(const float* __restrict__ ef,
                                                const int* __restrict__ row_start,
                                                const int* __restrict__ eid,
                                                float* __restrict__ nx) {
    int lane = threadIdx.x & 63;
    int n = blockIdx.x * 4 + (threadIdx.x >> 6);
    if (n >= NN) return;
    int beg = row_start[n], end = row_start[n + 1];
    float a0 = 0.f, a1 = 0.f;
    int i = beg;
    for (; i + 1 < end; i += 2) {
        int e0 = eid[i], e1 = eid[i + 1];
        a0 += ef[(long)e0 * DD + lane];
        a1 += ef[(long)e1 * DD + lane];
    }
    if (i < end) {
        int e0 = eid[i];
        a0 += ef[(long)e0 * DD + lane];
    }
    nx[(long)n * DD + lane] = a0 + a1;
}

// ---- h_pre = node_x @ W1 (per-node) ----
__global__ __launch_bounds__(256) void k_node_mlp(const float* __restrict__ nx,
                                                  const float* __restrict__ W1T,
                                                  float* __restrict__ hp) {
    int n = blockIdx.x * 256 + threadIdx.x;
    if (n >= NN) return;
    float x[DD];
    const float4* xr = (const float4*)(nx + (long)n * DD);
#pragma unroll
    for (int i = 0; i < DD / 4; ++i) {
        float4 v = xr[i];
        x[4 * i + 0] = v.x; x[4 * i + 1] = v.y;
        x[4 * i + 2] = v.z; x[4 * i + 3] = v.w;
    }
    float4* o = (float4*)(hp + (long)n * DD);
    for (int j = 0; j < DD; j += 4) {
        const float* w0 = W1T + (j + 0) * DD;
        const float* w1 = W1T + (j + 1) * DD;
        const float* w2 = W1T + (j + 2) * DD;
        const float* w3 = W1T + (j + 3) * DD;
        float a0 = 0.f, a1 = 0.f, a2 = 0.f, a3 = 0.f;
#pragma unroll
        for (int k = 0; k < DD; ++k) {
            float hk = x[k];
            a0 = fmaf(hk, w0[k], a0);
            a1 = fmaf(hk, w1[k], a1);
            a2 = fmaf(hk, w2[k], a2);
            a3 = fmaf(hk, w3[k], a3);
        }
        float4 r; r.x = a0; r.y = a1; r.z = a2; r.w = a3;
        o[j >> 2] = r;
    }
}

// ---- edge_out = 0.5 * (relu(h_pre[src] + h_pre[dst] + b1) @ W2 + b2) ----
__global__ __launch_bounds__(256) void k_edge_mlp(const float* __restrict__ hp,
                                                  const int* __restrict__ src,
                                                  const int* __restrict__ dst,
                                                  const float* __restrict__ b1,
                                                  const float* __restrict__ W2T,
                                                  const float* __restrict__ b2,
                                                  float* __restrict__ out) {
    int e = blockIdx.x * 256 + threadIdx.x;
    if (e >= NE) return;
    int s = src[e], d = dst[e];
    const float4* ps = (const float4*)(hp + (long)s * DD);
    const float4* pd = (const float4*)(hp + (long)d * DD);
    float h[DD];
#pragma unroll
    for (int i = 0; i < DD / 4; ++i) {
        float4 a = ps[i];
        float4 b = pd[i];
        float4 bb = ((const float4*)b1)[i];
        h[4 * i + 0] = fmaxf(a.x + b.x + bb.x, 0.f);
        h[4 * i + 1] = fmaxf(a.y + b.y + bb.y, 0.f);
        h[4 * i + 2] = fmaxf(a.z + b.z + bb.z, 0.f);
        h[4 * i + 3] = fmaxf(a.w + b.w + bb.w, 0.f);
    }
    float4* o = (float4*)(out + (long)e * DD);
    for (int j = 0; j < DD; j += 4) {
        const float* w0 = W2T + (j + 0) * DD;
        const float* w1 = W2T + (j + 1) * DD;
        const float* w2 = W2T + (j + 2) * DD;
        const float* w3 = W2T + (j + 3) * DD;
        float a0 = b2[j + 0], a1 = b2[j + 1], a2 = b2[j + 2], a3 = b2[j + 3];
#pragma unroll
        for (int k = 0; k < DD; ++k) {
            float hk = h[k];
            a0 = fmaf(hk, w0[k], a0);
            a1 = fmaf(hk, w1[k], a1);
            a2 = fmaf(hk, w2[k], a2);
            a3 = fmaf(hk, w3[k], a3);
        }
        float4 r;
        r.x = 0.5f * a0; r.y = 0.5f * a1; r.z = 0.5f * a2; r.w = 0.5f * a3;
        o[j >> 2] = r;
    }
}

extern "C" void kernel_launch(void* const* d_in, const int* in_sizes, int n_in,
                              void* d_out, int out_size, void* d_ws, size_t ws_size,
                              hipStream_t stream) {
    const float* edge_feat = (const float*)d_in[0];
    const int*   src       = (const int*)d_in[1];
    const int*   dst       = (const int*)d_in[2];
    const float* W1        = (const float*)d_in[3];
    const float* b1        = (const float*)d_in[4];
    const float* W2        = (const float*)d_in[5];
    const float* b2        = (const float*)d_in[6];
    float* out = (float*)d_out;

    char* ws = (char*)d_ws;
    size_t off = 0;
    float* node_x = (float*)(ws + off); off += (size_t)NN * DD * 4;   // 12.8 MB
    float* h_pre  = (float*)(ws + off); off += (size_t)NN * DD * 4;   // 12.8 MB
    float* W1T    = (float*)(ws + off); off += DD * DD * 4;
    float* W2T    = (float*)(ws + off); off += DD * DD * 4;
    int* cnt       = (int*)(ws + off); off += (size_t)NN * 4;
    int* row_start = (int*)(ws + off); off += (size_t)(NN + 1) * 4;
    int* cursor    = (int*)(ws + off); off += (size_t)NN * 4;
    int* bsum      = (int*)(ws + off); off += 256 * 4;
    int* eid       = (int*)(ws + off); off += (size_t)NE * 4;         // 3.2 MB

    hipMemsetAsync(cnt, 0, (size_t)NN * 4, stream);
    k_transpose<<<(DD * DD + 255) / 256, 256, 0, stream>>>(W1, W2, W1T, W2T);
    k_hist<<<(NE + 255) / 256, 256, 0, stream>>>(dst, cnt);
    k_block_sum<<<NB, 256, 0, stream>>>(cnt, bsum);
    k_scan_bsum<<<1, 256, 0, stream>>>(bsum);
    k_scan_final<<<NB, 256, 0, stream>>>(cnt, bsum, row_start, cursor);
    k_reorder<<<(NE + 255) / 256, 256, 0, stream>>>(dst, cursor, eid);
    k_gather<<<(NN + 3) / 4, 256, 0, stream>>>(edge_feat, row_start, eid, node_x);
    k_node_mlp<<<(NN + 255) / 256, 256, 0, stream>>>(node_x, W1T, h_pre);
    k_edge_mlp<<<(NE + 255) / 256, 256, 0, stream>>>(h_pre, src, dst, b1, W2T, b2, out);
}

// Round 3
// 709.212 us; speedup vs baseline: 1.7107x; 1.0358x over previous
//
#include <hip/hip_runtime.h>

#define NN 50000
#define NE 800000
#define DD 64
#define NB 196   // ceil(NN/256)

// ---- CSR build: histogram of dst ----
__global__ __launch_bounds__(256) void k_hist(const int* __restrict__ dst,
                                              int* __restrict__ cnt) {
    int e = blockIdx.x * 256 + threadIdx.x;
    if (e < NE) atomicAdd(&cnt[dst[e]], 1);
}

// ---- scan pass 1: per-block sums of cnt ----
__global__ __launch_bounds__(256) void k_block_sum(const int* __restrict__ cnt,
                                                   int* __restrict__ bsum) {
    __shared__ int s[256];
    int i = blockIdx.x * 256 + threadIdx.x;
    s[threadIdx.x] = (i < NN) ? cnt[i] : 0;
    __syncthreads();
    for (int o = 128; o > 0; o >>= 1) {
        if (threadIdx.x < o) s[threadIdx.x] += s[threadIdx.x + o];
        __syncthreads();
    }
    if (threadIdx.x == 0) bsum[blockIdx.x] = s[0];
}

// ---- scan pass 2: exclusive scan of NB block sums (single block) ----
__global__ __launch_bounds__(256) void k_scan_bsum(int* __restrict__ bsum) {
    __shared__ int s[256];
    int t = threadIdx.x;
    int v = (t < NB) ? bsum[t] : 0;
    s[t] = v;
    __syncthreads();
    for (int o = 1; o < 256; o <<= 1) {
        int x = (t >= o) ? s[t - o] : 0;
        __syncthreads();
        s[t] += x;
        __syncthreads();
    }
    if (t < NB) bsum[t] = s[t] - v;  // exclusive
}

// ---- scan pass 3: final exclusive offsets; write row_start and cursor ----
__global__ __launch_bounds__(256) void k_scan_final(const int* __restrict__ cnt,
                                                    const int* __restrict__ bsum,
                                                    int* __restrict__ row_start,
                                                    int* __restrict__ cursor) {
    __shared__ int s[256];
    int t = threadIdx.x;
    int i = blockIdx.x * 256 + t;
    int v = (i < NN) ? cnt[i] : 0;
    s[t] = v;
    __syncthreads();
    for (int o = 1; o < 256; o <<= 1) {
        int x = (t >= o) ? s[t - o] : 0;
        __syncthreads();
        s[t] += x;
        __syncthreads();
    }
    int excl = s[t] - v + bsum[blockIdx.x];
    if (i < NN) {
        row_start[i] = excl;
        cursor[i]    = excl;
        if (i == NN - 1) row_start[NN] = excl + v;  // == NE
    }
}

// ---- counting sort: scatter edge ids into dst-sorted order ----
__global__ __launch_bounds__(256) void k_reorder(const int* __restrict__ dst,
                                                 int* __restrict__ cursor,
                                                 int* __restrict__ eid) {
    int e = blockIdx.x * 256 + threadIdx.x;
    if (e < NE) {
        int pos = atomicAdd(&cursor[dst[e]], 1);
        eid[pos] = e;
    }
}

// ---- gather-sum: one wave per node, lane l accumulates feature l ----
__global__ __launch_bounds__(256) void k_gather(const float* __restrict__ ef,
                                                const int* __restrict__ row_start,
                                                const int* __restrict__ eid,
                                                float* __restrict__ nx) {
    int lane = threadIdx.x & 63;
    int n = blockIdx.x * 4 + (threadIdx.x >> 6);
    if (n >= NN) return;
    int beg = row_start[n], end = row_start[n + 1];
    float a0 = 0.f, a1 = 0.f, a2 = 0.f, a3 = 0.f;
    int i = beg;
    for (; i + 3 < end; i += 4) {
        int e0 = eid[i], e1 = eid[i + 1], e2 = eid[i + 2], e3 = eid[i + 3];
        a0 += ef[(long)e0 * DD + lane];
        a1 += ef[(long)e1 * DD + lane];
        a2 += ef[(long)e2 * DD + lane];
        a3 += ef[(long)e3 * DD + lane];
    }
    for (; i < end; ++i) {
        a0 += ef[(long)eid[i] * DD + lane];
    }
    nx[(long)n * DD + lane] = (a0 + a1) + (a2 + a3);
}

// ---- h_pre = node_x @ W1, k-outer / 64-accumulator (no spill, no transpose) ----
__global__ __launch_bounds__(256, 4) void k_node_mlp(const float* __restrict__ nx,
                                                     const float* __restrict__ W1,
                                                     float* __restrict__ hp) {
    int n = blockIdx.x * 256 + threadIdx.x;
    if (n >= NN) return;
    const float4* xr = (const float4*)(nx + (long)n * DD);
    float acc[DD];
#pragma unroll
    for (int j = 0; j < DD; ++j) acc[j] = 0.f;
#pragma unroll
    for (int kc = 0; kc < DD / 4; ++kc) {
        float4 x = xr[kc];
        const float* w0 = W1 + (4 * kc + 0) * DD;  // wave-uniform rows -> s_load
        const float* w1 = W1 + (4 * kc + 1) * DD;
        const float* w2 = W1 + (4 * kc + 2) * DD;
        const float* w3 = W1 + (4 * kc + 3) * DD;
#pragma unroll
        for (int j = 0; j < DD; ++j) {
            float a = acc[j];
            a = fmaf(x.x, w0[j], a);
            a = fmaf(x.y, w1[j], a);
            a = fmaf(x.z, w2[j], a);
            a = fmaf(x.w, w3[j], a);
            acc[j] = a;
        }
    }
    float4* o = (float4*)(hp + (long)n * DD);
#pragma unroll
    for (int j = 0; j < DD; j += 4) {
        float4 r;
        r.x = acc[j + 0]; r.y = acc[j + 1]; r.z = acc[j + 2]; r.w = acc[j + 3];
        o[j >> 2] = r;
    }
}

// ---- edge_out = 0.5*(relu(h_pre[src]+h_pre[dst]+b1) @ W2 + b2), k-outer ----
__global__ __launch_bounds__(256, 4) void k_edge_mlp(const float* __restrict__ hp,
                                                     const int* __restrict__ src,
                                                     const int* __restrict__ dst,
                                                     const float* __restrict__ b1,
                                                     const float* __restrict__ W2,
                                                     const float* __restrict__ b2,
                                                     float* __restrict__ out) {
    int e = blockIdx.x * 256 + threadIdx.x;
    if (e >= NE) return;
    int s = src[e], d = dst[e];
    const float4* ps = (const float4*)(hp + (long)s * DD);
    const float4* pd = (const float4*)(hp + (long)d * DD);
    float acc[DD];
#pragma unroll
    for (int j = 0; j < DD; ++j) acc[j] = 0.f;
#pragma unroll
    for (int kc = 0; kc < DD / 4; ++kc) {
        float4 a = ps[kc];
        float4 b = pd[kc];
        float4 bb = ((const float4*)b1)[kc];   // uniform -> s_load
        float h0 = fmaxf(a.x + b.x + bb.x, 0.f);
        float h1 = fmaxf(a.y + b.y + bb.y, 0.f);
        float h2 = fmaxf(a.z + b.z + bb.z, 0.f);
        float h3 = fmaxf(a.w + b.w + bb.w, 0.f);
        const float* w0 = W2 + (4 * kc + 0) * DD;  // wave-uniform rows -> s_load
        const float* w1 = W2 + (4 * kc + 1) * DD;
        const float* w2 = W2 + (4 * kc + 2) * DD;
        const float* w3 = W2 + (4 * kc + 3) * DD;
#pragma unroll
        for (int j = 0; j < DD; ++j) {
            float v = acc[j];
            v = fmaf(h0, w0[j], v);
            v = fmaf(h1, w1[j], v);
            v = fmaf(h2, w2[j], v);
            v = fmaf(h3, w3[j], v);
            acc[j] = v;
        }
    }
    float4* o = (float4*)(out + (long)e * DD);
#pragma unroll
    for (int j = 0; j < DD; j += 4) {
        float4 r;
        r.x = 0.5f * (acc[j + 0] + b2[j + 0]);
        r.y = 0.5f * (acc[j + 1] + b2[j + 1]);
        r.z = 0.5f * (acc[j + 2] + b2[j + 2]);
        r.w = 0.5f * (acc[j + 3] + b2[j + 3]);
        o[j >> 2] = r;
    }
}

extern "C" void kernel_launch(void* const* d_in, const int* in_sizes, int n_in,
                              void* d_out, int out_size, void* d_ws, size_t ws_size,
                              hipStream_t stream) {
    const float* edge_feat = (const float*)d_in[0];
    const int*   src       = (const int*)d_in[1];
    const int*   dst       = (const int*)d_in[2];
    const float* W1        = (const float*)d_in[3];
    const float* b1        = (const float*)d_in[4];
    const float* W2        = (const float*)d_in[5];
    const float* b2        = (const float*)d_in[6];
    float* out = (float*)d_out;

    char* ws = (char*)d_ws;
    size_t off = 0;
    float* node_x = (float*)(ws + off); off += (size_t)NN * DD * 4;   // 12.8 MB
    float* h_pre  = (float*)(ws + off); off += (size_t)NN * DD * 4;   // 12.8 MB
    int* cnt       = (int*)(ws + off); off += (size_t)NN * 4;
    int* row_start = (int*)(ws + off); off += (size_t)(NN + 1) * 4;
    int* cursor    = (int*)(ws + off); off += (size_t)NN * 4;
    int* bsum      = (int*)(ws + off); off += 256 * 4;
    int* eid       = (int*)(ws + off); off += (size_t)NE * 4;         // 3.2 MB

    hipMemsetAsync(cnt, 0, (size_t)NN * 4, stream);
    k_hist<<<(NE + 255) / 256, 256, 0, stream>>>(dst, cnt);
    k_block_sum<<<NB, 256, 0, stream>>>(cnt, bsum);
    k_scan_bsum<<<1, 256, 0, stream>>>(bsum);
    k_scan_final<<<NB, 256, 0, stream>>>(cnt, bsum, row_start, cursor);
    k_reorder<<<(NE + 255) / 256, 256, 0, stream>>>(dst, cursor, eid);
    k_gather<<<(NN + 3) / 4, 256, 0, stream>>>(edge_feat, row_start, eid, node_x);
    k_node_mlp<<<(NN + 255) / 256, 256, 0, stream>>>(node_x, W1, h_pre);
    k_edge_mlp<<<(NE + 255) / 256, 256, 0, stream>>>(h_pre, src, dst, b1, W2, b2, out);
}